// Round 2
// baseline (10840.483 us; speedup 1.0000x reference)
//
#include <hip/hip_runtime.h>

#define NN   100000
#define VFD  128
#define FILT 64
#define NH   3
#define KK   10
#define OUTC (NH * FILT)   // 192

// ---------------------------------------------------------------------------
// Pass 1: per-branch GEMM. Computes Zc (written into d_out region) and
// Zn_src (workspace), plus fused dot products:
//   c2[h][n] = Zc[h,n,:]  . a2[h]   (a2 = a[h][64:128])
//   s1[h][n] = Zn_src[h,n,:] . a1[h] (a1 = a[h][0:64])
// Tile: 64 rows x 64 cols per chunk; 6 chunks = {Wvc,Wvn} x 3 heads.
// Microtile 4x4/thread, row = tr+16r, col = tc+16c. LDS stride 132 =>
// av reads are 16-lane broadcasts over 4 distinct banks, bw reads 2-way
// aliased (free per bank model).
// ---------------------------------------------------------------------------
__global__ __launch_bounds__(256, 2) void gat_pass1(
    const float* __restrict__ vert, const int* __restrict__ is_int, int want,
    const float* __restrict__ Wvc, const float* __restrict__ Wvn,
    const float* __restrict__ avec,          // [NH][2*FILT]
    float* __restrict__ zc_out,              // [n][h][FILT]  (d_out region)
    float* __restrict__ zn_src,              // [n][h][FILT]  (ws)
    float* __restrict__ s1, float* __restrict__ c2)  // [h][NN]
{
    __shared__ __align__(16) float vt[64][132];
    __shared__ __align__(16) float wt[64][132];

    const int tid  = threadIdx.x;
    const int row0 = blockIdx.x * 64;
    const int tr   = tid >> 4;   // 0..15
    const int tc   = tid & 15;   // 0..15

    // ---- stage v tile (masked by is_int==want), float4, coalesced ----
#pragma unroll
    for (int i = 0; i < 8; ++i) {
        int idx4 = i * 256 + tid;       // 0..2047
        int r    = idx4 >> 5;           // row in tile
        int f4   = idx4 & 31;           // float4 index within row
        int n    = row0 + r;
        float4 val = make_float4(0.f, 0.f, 0.f, 0.f);
        if (n < NN && is_int[n] == want)
            val = *reinterpret_cast<const float4*>(vert + (size_t)n * VFD + f4 * 4);
        *reinterpret_cast<float4*>(&vt[r][f4 * 4]) = val;
    }

    for (int m = 0; m < 2; ++m) {
        const float* Wbase = (m == 0) ? Wvc : Wvn;
        for (int h = 0; h < NH; ++h) {
            const float* W = Wbase + (size_t)h * VFD * FILT;
            // ---- stage W transposed: wt[c][f] = W[f][c] ----
#pragma unroll
            for (int i = 0; i < 8; ++i) {
                int idx4 = i * 256 + tid;   // 0..2047
                int f    = idx4 >> 4;       // 0..127
                int c4   = idx4 & 15;
                float4 wv = *reinterpret_cast<const float4*>(W + f * FILT + c4 * 4);
                wt[c4 * 4 + 0][f] = wv.x;
                wt[c4 * 4 + 1][f] = wv.y;
                wt[c4 * 4 + 2][f] = wv.z;
                wt[c4 * 4 + 3][f] = wv.w;
            }
            __syncthreads();

            float acc[4][4];
#pragma unroll
            for (int r = 0; r < 4; ++r)
#pragma unroll
                for (int c = 0; c < 4; ++c) acc[r][c] = 0.f;

#pragma unroll
            for (int f = 0; f < VFD; f += 4) {
                float4 av[4], bw[4];
#pragma unroll
                for (int r = 0; r < 4; ++r)
                    av[r] = *reinterpret_cast<const float4*>(&vt[tr + 16 * r][f]);
#pragma unroll
                for (int c = 0; c < 4; ++c)
                    bw[c] = *reinterpret_cast<const float4*>(&wt[tc + 16 * c][f]);
#pragma unroll
                for (int r = 0; r < 4; ++r)
#pragma unroll
                    for (int c = 0; c < 4; ++c) {
                        acc[r][c] = fmaf(av[r].x, bw[c].x, acc[r][c]);
                        acc[r][c] = fmaf(av[r].y, bw[c].y, acc[r][c]);
                        acc[r][c] = fmaf(av[r].z, bw[c].z, acc[r][c]);
                        acc[r][c] = fmaf(av[r].w, bw[c].w, acc[r][c]);
                    }
            }

            // ---- write tile + fused row-dot with a1/a2 ----
            float* optr = (m == 0) ? zc_out : zn_src;
            const float* ap = avec + h * 2 * FILT + ((m == 0) ? FILT : 0);
            float part[4] = {0.f, 0.f, 0.f, 0.f};
#pragma unroll
            for (int c = 0; c < 4; ++c) {
                float aval = ap[tc + 16 * c];
#pragma unroll
                for (int r = 0; r < 4; ++r) part[r] = fmaf(acc[r][c], aval, part[r]);
            }
#pragma unroll
            for (int r = 0; r < 4; ++r) {
                int n = row0 + tr + 16 * r;
                if (n < NN) {
                    float* dst = optr + (size_t)n * OUTC + h * FILT;
#pragma unroll
                    for (int c = 0; c < 4; ++c) dst[tc + 16 * c] = acc[r][c];
                }
            }
            // reduce part[] across the 16 tc lanes (contiguous within wave)
#pragma unroll
            for (int mask = 1; mask < 16; mask <<= 1)
#pragma unroll
                for (int r = 0; r < 4; ++r)
                    part[r] += __shfl_xor(part[r], mask, 64);
            if (tc == 0) {
                float* sdst = (m == 0) ? c2 : s1;
#pragma unroll
                for (int r = 0; r < 4; ++r) {
                    int n = row0 + tr + 16 * r;
                    if (n < NN) sdst[h * NN + n] = part[r];
                }
            }
            __syncthreads();
        }
    }
}

// ---------------------------------------------------------------------------
// Pass 2: one wave per node. All lanes replicate the K=10 softmax from
// broadcast loads; each lane owns output elements (h, f=lane).
//   e[h,k] = (s1[h,idx[k]] + c2[h,n]) * part_k * edge_k   (0 when idx==-1)
//   alpha  = softmax_k(e);  weight = alpha * part / max(sum(part),1)
//   Zn[h,f] = sum_k zn_src[idx[k]][h][f] * weight
//   out = relu(Zc + Zn + bv)
// ---------------------------------------------------------------------------
__global__ __launch_bounds__(256) void gat_pass2(
    const int* __restrict__ nidx, const float* __restrict__ edges,
    const float* __restrict__ zn_src, const float* __restrict__ s1,
    const float* __restrict__ c2, const float* __restrict__ bv,
    float* __restrict__ out)
{
    const int lane = threadIdx.x & 63;
    const int n    = (int)((blockIdx.x * blockDim.x + threadIdx.x) >> 6);
    if (n >= NN) return;

    int   id[KK];
    float ed[KK];
#pragma unroll
    for (int k = 0; k < KK; ++k) {
        id[k] = nidx[n * KK + k];
        ed[k] = edges[n * KK + k];
    }
    float npart = 0.f;
#pragma unroll
    for (int k = 0; k < KK; ++k)
        if (id[k] >= 0) npart += 1.f;
    const float norm = fmaxf(npart, 1.f);

    float zacc[NH];
#pragma unroll
    for (int h = 0; h < NH; ++h) {
        const float c2v = c2[h * NN + n];
        float e[KK];
#pragma unroll
        for (int k = 0; k < KK; ++k)
            e[k] = (id[k] >= 0) ? (s1[h * NN + id[k]] + c2v) * ed[k] : 0.f;
        float mx = e[0];
#pragma unroll
        for (int k = 1; k < KK; ++k) mx = fmaxf(mx, e[k]);
        float w[KK];
        float den = 0.f;
#pragma unroll
        for (int k = 0; k < KK; ++k) {
            w[k] = __expf(e[k] - mx);
            den += w[k];
        }
        const float scale = 1.f / (den * norm);
        float acc = 0.f;
#pragma unroll
        for (int k = 0; k < KK; ++k) {
            if (id[k] >= 0) {
                float g = zn_src[(size_t)id[k] * OUTC + h * FILT + lane];
                acc = fmaf(g, w[k] * scale, acc);
            }
        }
        zacc[h] = acc;
    }

    float* orow = out + (size_t)n * OUTC;
#pragma unroll
    for (int h = 0; h < NH; ++h) {
        float zc  = orow[h * FILT + lane];
        float res = zc + zacc[h] + bv[h * FILT + lane];
        orow[h * FILT + lane] = fmaxf(res, 0.f);
    }
}

// ---------------------------------------------------------------------------
extern "C" void kernel_launch(void* const* d_in, const int* in_sizes, int n_in,
                              void* d_out, int out_size, void* d_ws, size_t ws_size,
                              hipStream_t stream)
{
    const float* v_int  = (const float*)d_in[0];
    const float* v_nh   = (const float*)d_in[1];
    const int*   nh_idx = (const int*)d_in[2];
    const int*   in_idx = (const int*)d_in[3];
    const float* nh_e   = (const float*)d_in[4];
    const float* in_e   = (const float*)d_in[5];
    const int*   is_int = (const int*)d_in[6];
    const float* Wvc_i  = (const float*)d_in[7];
    const float* Wvc_n  = (const float*)d_in[8];
    const float* Wvn_i  = (const float*)d_in[9];
    const float* Wvn_n  = (const float*)d_in[10];
    const float* bv_i   = (const float*)d_in[11];
    const float* bv_n   = (const float*)d_in[12];
    const float* a_i    = (const float*)d_in[13];
    const float* a_n    = (const float*)d_in[14];

    float* out  = (float*)d_out;
    float* out2 = out + (size_t)NN * OUTC;

    // workspace: Zn_src (NN*OUTC) + s1 (NH*NN) + c2 (NH*NN)  ~= 79.2 MB
    float* zn_src = (float*)d_ws;
    float* s1     = zn_src + (size_t)NN * OUTC;
    float* c2     = s1 + (size_t)NH * NN;

    dim3 b(256);
    dim3 g1((NN + 63) / 64);
    dim3 g2((NN * 64 + 255) / 256);

    // int branch (mask: is_int == 1)
    gat_pass1<<<g1, b, 0, stream>>>(v_int, is_int, 1, Wvc_i, Wvn_i, a_i,
                                    out, zn_src, s1, c2);
    gat_pass2<<<g2, b, 0, stream>>>(in_idx, in_e, zn_src, s1, c2, bv_i, out);

    // nh branch (mask: is_int == 0), reuses workspace
    gat_pass1<<<g1, b, 0, stream>>>(v_nh, is_int, 0, Wvc_n, Wvn_n, a_n,
                                    out2, zn_src, s1, c2);
    gat_pass2<<<g2, b, 0, stream>>>(nh_idx, nh_e, zn_src, s1, c2, bv_n, out2);
}

// Round 3
// 1100.962 us; speedup vs baseline: 9.8464x; 9.8464x over previous
//
#include <hip/hip_runtime.h>

#define NN   100000
#define VFD  128
#define FILT 64
#define NH   3
#define KK   10
#define OUTC (NH * FILT)   // 192

// ---------------------------------------------------------------------------
// Pass 1: per-branch GEMM. Computes Zc (written into d_out region) and
// Zn_src (workspace), plus fused dot products:
//   c2[h][n] = Zc[h,n,:]  . a2[h]   (a2 = a[h][64:128])
//   s1[h][n] = Zn_src[h,n,:] . a1[h] (a1 = a[h][0:64])
// Tile: 64 rows x 64 cols per chunk; 6 chunks = {Wvc,Wvn} x 3 heads.
// Microtile 4x4/thread, row = tr+16r, col = tc+16c.
// R2 change: f-loop pinned to `#pragma unroll 2`. Full unroll (32 trips)
// made LLVM hoist ~1024 dwords of LDS loads -> ~700 dw/thread scratch spill
// -> 14 GB of symmetric HBM R/W traffic per dispatch (measured R1: FETCH ==
// WRITE == 6.87e6 KB, VALUBusy 2.6%, dur 5.07 ms). unroll 2 keeps ~90 live
// dwords, no spill.
// ---------------------------------------------------------------------------
__global__ __launch_bounds__(256, 2) void gat_pass1(
    const float* __restrict__ vert, const int* __restrict__ is_int, int want,
    const float* __restrict__ Wvc, const float* __restrict__ Wvn,
    const float* __restrict__ avec,          // [NH][2*FILT]
    float* __restrict__ zc_out,              // [n][h][FILT]  (d_out region)
    float* __restrict__ zn_src,              // [n][h][FILT]  (ws)
    float* __restrict__ s1, float* __restrict__ c2)  // [h][NN]
{
    __shared__ __align__(16) float vt[64][132];
    __shared__ __align__(16) float wt[64][132];

    const int tid  = threadIdx.x;
    const int row0 = blockIdx.x * 64;
    const int tr   = tid >> 4;   // 0..15
    const int tc   = tid & 15;   // 0..15

    // ---- stage v tile (masked by is_int==want), float4, coalesced ----
#pragma unroll
    for (int i = 0; i < 8; ++i) {
        int idx4 = i * 256 + tid;       // 0..2047
        int r    = idx4 >> 5;           // row in tile
        int f4   = idx4 & 31;           // float4 index within row
        int n    = row0 + r;
        float4 val = make_float4(0.f, 0.f, 0.f, 0.f);
        if (n < NN && is_int[n] == want)
            val = *reinterpret_cast<const float4*>(vert + (size_t)n * VFD + f4 * 4);
        *reinterpret_cast<float4*>(&vt[r][f4 * 4]) = val;
    }

    for (int m = 0; m < 2; ++m) {
        const float* Wbase = (m == 0) ? Wvc : Wvn;
        for (int h = 0; h < NH; ++h) {
            const float* W = Wbase + (size_t)h * VFD * FILT;
            // ---- stage W transposed: wt[c][f] = W[f][c] ----
#pragma unroll
            for (int i = 0; i < 8; ++i) {
                int idx4 = i * 256 + tid;   // 0..2047
                int f    = idx4 >> 4;       // 0..127
                int c4   = idx4 & 15;
                float4 wv = *reinterpret_cast<const float4*>(W + f * FILT + c4 * 4);
                wt[c4 * 4 + 0][f] = wv.x;
                wt[c4 * 4 + 1][f] = wv.y;
                wt[c4 * 4 + 2][f] = wv.z;
                wt[c4 * 4 + 3][f] = wv.w;
            }
            __syncthreads();

            float acc[4][4];
#pragma unroll
            for (int r = 0; r < 4; ++r)
#pragma unroll
                for (int c = 0; c < 4; ++c) acc[r][c] = 0.f;

            // R2: unroll 2 (was full unroll -> scratch spill, see header)
#pragma unroll 2
            for (int f = 0; f < VFD; f += 4) {
                float4 av[4], bw[4];
#pragma unroll
                for (int r = 0; r < 4; ++r)
                    av[r] = *reinterpret_cast<const float4*>(&vt[tr + 16 * r][f]);
#pragma unroll
                for (int c = 0; c < 4; ++c)
                    bw[c] = *reinterpret_cast<const float4*>(&wt[tc + 16 * c][f]);
#pragma unroll
                for (int r = 0; r < 4; ++r)
#pragma unroll
                    for (int c = 0; c < 4; ++c) {
                        acc[r][c] = fmaf(av[r].x, bw[c].x, acc[r][c]);
                        acc[r][c] = fmaf(av[r].y, bw[c].y, acc[r][c]);
                        acc[r][c] = fmaf(av[r].z, bw[c].z, acc[r][c]);
                        acc[r][c] = fmaf(av[r].w, bw[c].w, acc[r][c]);
                    }
            }

            // ---- write tile + fused row-dot with a1/a2 ----
            float* optr = (m == 0) ? zc_out : zn_src;
            const float* ap = avec + h * 2 * FILT + ((m == 0) ? FILT : 0);
            float part[4] = {0.f, 0.f, 0.f, 0.f};
#pragma unroll
            for (int c = 0; c < 4; ++c) {
                float aval = ap[tc + 16 * c];
#pragma unroll
                for (int r = 0; r < 4; ++r) part[r] = fmaf(acc[r][c], aval, part[r]);
            }
#pragma unroll
            for (int r = 0; r < 4; ++r) {
                int n = row0 + tr + 16 * r;
                if (n < NN) {
                    float* dst = optr + (size_t)n * OUTC + h * FILT;
#pragma unroll
                    for (int c = 0; c < 4; ++c) dst[tc + 16 * c] = acc[r][c];
                }
            }
            // reduce part[] across the 16 tc lanes (contiguous within wave)
#pragma unroll
            for (int mask = 1; mask < 16; mask <<= 1)
#pragma unroll
                for (int r = 0; r < 4; ++r)
                    part[r] += __shfl_xor(part[r], mask, 64);
            if (tc == 0) {
                float* sdst = (m == 0) ? c2 : s1;
#pragma unroll
                for (int r = 0; r < 4; ++r) {
                    int n = row0 + tr + 16 * r;
                    if (n < NN) sdst[h * NN + n] = part[r];
                }
            }
            __syncthreads();
        }
    }
}

// ---------------------------------------------------------------------------
// Pass 2: one wave per node. All lanes replicate the K=10 softmax from
// broadcast loads; each lane owns output elements (h, f=lane).
//   e[h,k] = (s1[h,idx[k]] + c2[h,n]) * part_k * edge_k   (0 when idx==-1)
//   alpha  = softmax_k(e);  weight = alpha * part / max(sum(part),1)
//   Zn[h,f] = sum_k zn_src[idx[k]][h][f] * weight
//   out = relu(Zc + Zn + bv)
// ---------------------------------------------------------------------------
__global__ __launch_bounds__(256) void gat_pass2(
    const int* __restrict__ nidx, const float* __restrict__ edges,
    const float* __restrict__ zn_src, const float* __restrict__ s1,
    const float* __restrict__ c2, const float* __restrict__ bv,
    float* __restrict__ out)
{
    const int lane = threadIdx.x & 63;
    const int n    = (int)((blockIdx.x * blockDim.x + threadIdx.x) >> 6);
    if (n >= NN) return;

    int   id[KK];
    float ed[KK];
#pragma unroll
    for (int k = 0; k < KK; ++k) {
        id[k] = nidx[n * KK + k];
        ed[k] = edges[n * KK + k];
    }
    float npart = 0.f;
#pragma unroll
    for (int k = 0; k < KK; ++k)
        if (id[k] >= 0) npart += 1.f;
    const float norm = fmaxf(npart, 1.f);

    float zacc[NH];
#pragma unroll
    for (int h = 0; h < NH; ++h) {
        const float c2v = c2[h * NN + n];
        float e[KK];
#pragma unroll
        for (int k = 0; k < KK; ++k)
            e[k] = (id[k] >= 0) ? (s1[h * NN + id[k]] + c2v) * ed[k] : 0.f;
        float mx = e[0];
#pragma unroll
        for (int k = 1; k < KK; ++k) mx = fmaxf(mx, e[k]);
        float w[KK];
        float den = 0.f;
#pragma unroll
        for (int k = 0; k < KK; ++k) {
            w[k] = __expf(e[k] - mx);
            den += w[k];
        }
        const float scale = 1.f / (den * norm);
        float acc = 0.f;
#pragma unroll
        for (int k = 0; k < KK; ++k) {
            if (id[k] >= 0) {
                float g = zn_src[(size_t)id[k] * OUTC + h * FILT + lane];
                acc = fmaf(g, w[k] * scale, acc);
            }
        }
        zacc[h] = acc;
    }

    float* orow = out + (size_t)n * OUTC;
#pragma unroll
    for (int h = 0; h < NH; ++h) {
        float zc  = orow[h * FILT + lane];
        float res = zc + zacc[h] + bv[h * FILT + lane];
        orow[h * FILT + lane] = fmaxf(res, 0.f);
    }
}

// ---------------------------------------------------------------------------
extern "C" void kernel_launch(void* const* d_in, const int* in_sizes, int n_in,
                              void* d_out, int out_size, void* d_ws, size_t ws_size,
                              hipStream_t stream)
{
    const float* v_int  = (const float*)d_in[0];
    const float* v_nh   = (const float*)d_in[1];
    const int*   nh_idx = (const int*)d_in[2];
    const int*   in_idx = (const int*)d_in[3];
    const float* nh_e   = (const float*)d_in[4];
    const float* in_e   = (const float*)d_in[5];
    const int*   is_int = (const int*)d_in[6];
    const float* Wvc_i  = (const float*)d_in[7];
    const float* Wvc_n  = (const float*)d_in[8];
    const float* Wvn_i  = (const float*)d_in[9];
    const float* Wvn_n  = (const float*)d_in[10];
    const float* bv_i   = (const float*)d_in[11];
    const float* bv_n   = (const float*)d_in[12];
    const float* a_i    = (const float*)d_in[13];
    const float* a_n    = (const float*)d_in[14];

    float* out  = (float*)d_out;
    float* out2 = out + (size_t)NN * OUTC;

    // workspace: Zn_src (NN*OUTC) + s1 (NH*NN) + c2 (NH*NN)  ~= 79.2 MB
    float* zn_src = (float*)d_ws;
    float* s1     = zn_src + (size_t)NN * OUTC;
    float* c2     = s1 + (size_t)NH * NN;

    dim3 b(256);
    dim3 g1((NN + 63) / 64);
    dim3 g2((NN * 64 + 255) / 256);

    // int branch (mask: is_int == 1)
    gat_pass1<<<g1, b, 0, stream>>>(v_int, is_int, 1, Wvc_i, Wvn_i, a_i,
                                    out, zn_src, s1, c2);
    gat_pass2<<<g2, b, 0, stream>>>(in_idx, in_e, zn_src, s1, c2, bv_i, out);

    // nh branch (mask: is_int == 0), reuses workspace
    gat_pass1<<<g1, b, 0, stream>>>(v_nh, is_int, 0, Wvc_n, Wvn_n, a_n,
                                    out2, zn_src, s1, c2);
    gat_pass2<<<g2, b, 0, stream>>>(nh_idx, nh_e, zn_src, s1, c2, bv_n, out2);
}

// Round 4
// 584.060 us; speedup vs baseline: 18.5606x; 1.8850x over previous
//
#include <hip/hip_runtime.h>

// R3: pass1 rewritten as split-bf16 MFMA (hi/lo, 3 products ~ fp32 precision);
//     a1/a2 dots folded through GEMM via prep-computed wa = W·a;
//     W pre-transposed/split/swizzled into frag layout by prep kernel
//     (linear global_load_lds staging, swizzle pre-applied per rule #21).
//     pass2: unconditional clamped gathers issued before softmax (latency fix).
// R2: unroll-2 fixed scratch spill (FETCH 6.87e6 -> 0.38e6 KB).

#define NN   100000
#define VFD  128
#define FILT 64
#define NH   3
#define KK   10
#define OUTC 192
#define NB   ((NN + 63) / 64)   // 1563

typedef __attribute__((ext_vector_type(8))) short  short8;
typedef __attribute__((ext_vector_type(4))) float  f32x4;
typedef __attribute__((ext_vector_type(8))) __bf16 bf16x8;
typedef unsigned int u32;
typedef unsigned short u16;

static __device__ __forceinline__ f32x4 mfma_bf16(short8 a, short8 b, f32x4 c) {
    return __builtin_amdgcn_mfma_f32_16x16x32_bf16(
        __builtin_bit_cast(bf16x8, a), __builtin_bit_cast(bf16x8, b), c, 0, 0, 0);
}

// x == hi + lo up to 2^-16 relative (truncation split; residual exact in fp32)
static __device__ __forceinline__ void split2(float x, u16 &hi, u16 &lo) {
    u32 b = __float_as_uint(x);
    hi = (u16)(b >> 16);
    float hf = __uint_as_float(((u32)hi) << 16);
    lo = (u16)(__float_as_uint(x - hf) >> 16);
}

static __device__ __forceinline__ void gload16(const u32* g, u32* l) {
    __builtin_amdgcn_global_load_lds(
        (const __attribute__((address_space(1))) u32*)g,
        (__attribute__((address_space(3))) u32*)l, 16, 0, 0);
}

// ---- ws ushort-region layout (after float region) ----
// wt_ws[branch][chunk 6][plane 2][8192]   frag layout: granule g*64+(col^(g&7)), 8 k each
// wa_ws[branch][2048]                     linear [g16][col16][8]; cols: 0..2=c2(Wvc·a2), 3..5=s1(Wvn·a1)
#define WT_CH_STRIDE   (2 * 8192)
#define WT_BR_STRIDE   (6 * WT_CH_STRIDE)
#define WA_OFF         (2 * WT_BR_STRIDE)
#define WA_BR_STRIDE   2048
#define PREP_WT_ELEMS  (2 * 6 * 8192)   // 98304
#define PREP_WA_ELEMS  (2 * 16 * VFD)   // 4096

__global__ void gat_prep(
    const float* __restrict__ Wvc_i, const float* __restrict__ Wvn_i,
    const float* __restrict__ Wvc_n, const float* __restrict__ Wvn_n,
    const float* __restrict__ a_i,  const float* __restrict__ a_n,
    u16* __restrict__ wsu)
{
    int t = blockIdx.x * blockDim.x + threadIdx.x;
    if (t < PREP_WT_ELEMS) {
        int b  = t / (6 * 8192);
        int r  = t % (6 * 8192);
        int ch = r / 8192;
        int e  = r % 8192;
        int f = e >> 6, col = e & 63;
        int m = ch / 3, h = ch % 3;
        const float* W = b ? (m ? Wvn_n : Wvc_n) : (m ? Wvn_i : Wvc_i);
        float val = W[h * (VFD * FILT) + f * FILT + col];
        u16 hi, lo; split2(val, hi, lo);
        int g    = f >> 3;
        int gran = g * 64 + (col ^ (g & 7));
        int idx  = gran * 8 + (f & 7);
        u16* dst = wsu + b * WT_BR_STRIDE + ch * WT_CH_STRIDE;
        dst[idx]        = hi;
        dst[8192 + idx] = lo;
    } else if (t < PREP_WT_ELEMS + PREP_WA_ELEMS) {
        int r = t - PREP_WT_ELEMS;
        int b = r / 2048, e = r % 2048;
        int col = e >> 7, f = e & 127;
        const float* a  = b ? a_n  : a_i;
        const float* Wc = b ? Wvc_n : Wvc_i;
        const float* Wn = b ? Wvn_n : Wvn_i;
        float val = 0.f;
        if (col < 3) {                       // c2 col: Wvc[h] row f · a2[h]
            const float* wr = Wc + col * (VFD * FILT) + f * FILT;
            const float* av = a  + col * (2 * FILT) + FILT;
            for (int o = 0; o < FILT; ++o) val += wr[o] * av[o];
        } else if (col < 6) {                // s1 col: Wvn[h] row f · a1[h]
            int h = col - 3;
            const float* wr = Wn + h * (VFD * FILT) + f * FILT;
            const float* av = a  + h * (2 * FILT);
            for (int o = 0; o < FILT; ++o) val += wr[o] * av[o];
        }
        int idx = ((f >> 3) * 16 + col) * 8 + (f & 7);
        wsu[WA_OFF + b * WA_BR_STRIDE + idx] = (u16)(__float_as_uint(val) >> 16);
    }
}

// ---------------------------------------------------------------------------
// Pass 1: 64-row x 64-col tile per block, 4 waves as 2x2 (rw,cw), each wave
// 2x2 sub-tiles of 16x16, K=128 in 4 ksteps of 32. Split-bf16: 3 MFMA per
// (tile,kstep). vt/wt LDS frag layout: granule = g*64 + (row ^ (g&7)), 8
// bf16 per granule (bank-balanced for both frag reads and staging writes).
// Epilogue GEMV vs wa emits c2 (cols 0..2) / s1 (cols 3..5).
// ---------------------------------------------------------------------------
__global__ __launch_bounds__(256, 2) void gat_pass1(
    const float* __restrict__ vert, const int* __restrict__ is_int, int want,
    const u16* __restrict__ wt_ws, const u16* __restrict__ wa_ws,
    float* __restrict__ zc_out, float* __restrict__ zn_src,
    float* __restrict__ s1, float* __restrict__ c2)
{
    __shared__ __align__(16) u16 vt_hi[8192];
    __shared__ __align__(16) u16 vt_lo[8192];
    __shared__ __align__(16) u16 wt[2 * 8192];
    __shared__ __align__(16) u16 wa[2048];

    const int tid  = threadIdx.x;
    const int row0 = blockIdx.x * 64;
    const int w    = tid >> 6;
    const int lane = tid & 63;
    const int rw = w >> 1, cw = w & 1;
    const int l15 = lane & 15, l4 = lane >> 4;

    // ---- stage v: fp32 -> split bf16 into swizzled granules ----
#pragma unroll
    for (int i = 0; i < 8; ++i) {
        int idx4 = i * 256 + tid;
        int row = idx4 >> 5, f4 = idx4 & 31;
        int n = row0 + row;
        float4 val = make_float4(0.f, 0.f, 0.f, 0.f);
        if (n < NN && is_int[n] == want)
            val = *reinterpret_cast<const float4*>(vert + (size_t)n * VFD + f4 * 4);
        u16 h0,h1,h2,h3, q0,q1,q2,q3;
        split2(val.x, h0, q0); split2(val.y, h1, q1);
        split2(val.z, h2, q2); split2(val.w, h3, q3);
        int g    = f4 >> 1;
        int gran = g * 64 + (row ^ (g & 7));
        int uidx = gran * 8 + (f4 & 1) * 4;
        uint2 hv = make_uint2((u32)h0 | ((u32)h1 << 16), (u32)h2 | ((u32)h3 << 16));
        uint2 lv = make_uint2((u32)q0 | ((u32)q1 << 16), (u32)q2 | ((u32)q3 << 16));
        *reinterpret_cast<uint2*>(vt_hi + uidx) = hv;
        *reinterpret_cast<uint2*>(vt_lo + uidx) = lv;
    }
    // stage wa (4KB, linear copy)
    gload16((const u32*)(wa_ws + tid * 8), (u32*)(wa + tid * 8));

    for (int ch = 0; ch < 6; ++ch) {
        __syncthreads();                       // protect wt reads of prev chunk
        const u16* src = wt_ws + ch * WT_CH_STRIDE;
#pragma unroll
        for (int j = 0; j < 8; ++j) {
            int cblk = j * 256 + tid;
            gload16((const u32*)(src + cblk * 8), (u32*)(wt + cblk * 8));
        }
        __syncthreads();                       // wt (and iter-0: vt) ready

        const int m = ch / 3, h = ch % 3;
        f32x4 zero = {0.f, 0.f, 0.f, 0.f};
        f32x4 acc[2][2] = {{zero, zero}, {zero, zero}};

#pragma unroll
        for (int ks = 0; ks < 4; ++ks) {
            const int g = ks * 4 + l4;
            short8 ahi[2], alo[2], bhi[2], blo[2];
#pragma unroll
            for (int ti = 0; ti < 2; ++ti) {
                int row  = (rw * 2 + ti) * 16 + l15;
                int gran = g * 64 + (row ^ (g & 7));
                ahi[ti] = *reinterpret_cast<const short8*>(vt_hi + gran * 8);
                alo[ti] = *reinterpret_cast<const short8*>(vt_lo + gran * 8);
            }
#pragma unroll
            for (int tj = 0; tj < 2; ++tj) {
                int col  = (cw * 2 + tj) * 16 + l15;
                int gran = g * 64 + (col ^ (g & 7));
                bhi[tj] = *reinterpret_cast<const short8*>(wt + gran * 8);
                blo[tj] = *reinterpret_cast<const short8*>(wt + 8192 + gran * 8);
            }
#pragma unroll
            for (int ti = 0; ti < 2; ++ti)
#pragma unroll
                for (int tj = 0; tj < 2; ++tj) {
                    acc[ti][tj] = mfma_bf16(ahi[ti], bhi[tj], acc[ti][tj]);
                    acc[ti][tj] = mfma_bf16(ahi[ti], blo[tj], acc[ti][tj]);
                    acc[ti][tj] = mfma_bf16(alo[ti], bhi[tj], acc[ti][tj]);
                }
        }

        float* target = (m == 0) ? zc_out : zn_src;
#pragma unroll
        for (int ti = 0; ti < 2; ++ti)
#pragma unroll
            for (int tj = 0; tj < 2; ++tj) {
                int col = (cw * 2 + tj) * 16 + l15;
#pragma unroll
                for (int j = 0; j < 4; ++j) {
                    int n = row0 + (rw * 2 + ti) * 16 + l4 * 4 + j;
                    if (n < NN) target[(size_t)n * OUTC + h * FILT + col] = acc[ti][tj][j];
                }
            }
    }

    // ---- wa GEMV: c2/s1 via MFMA (D cols 0..5), vt unchanged since staging ----
    {
        f32x4 zero = {0.f, 0.f, 0.f, 0.f};
        f32x4 accS[2] = {zero, zero};
#pragma unroll
        for (int ks = 0; ks < 4; ++ks) {
            const int g = ks * 4 + l4;
            short8 wf = *reinterpret_cast<const short8*>(wa + (g * 16 + l15) * 8);
#pragma unroll
            for (int ti = 0; ti < 2; ++ti) {
                int row  = (rw * 2 + ti) * 16 + l15;
                int gran = g * 64 + (row ^ (g & 7));
                short8 ahi = *reinterpret_cast<const short8*>(vt_hi + gran * 8);
                short8 alo = *reinterpret_cast<const short8*>(vt_lo + gran * 8);
                accS[ti] = mfma_bf16(ahi, wf, accS[ti]);
                accS[ti] = mfma_bf16(alo, wf, accS[ti]);
            }
        }
        if (cw == 0 && l15 < 6) {
#pragma unroll
            for (int ti = 0; ti < 2; ++ti)
#pragma unroll
                for (int j = 0; j < 4; ++j) {
                    int n = row0 + (rw * 2 + ti) * 16 + l4 * 4 + j;
                    if (n < NN) {
                        float v = accS[ti][j];
                        if (l15 < 3) c2[l15 * NN + n] = v;
                        else         s1[(l15 - 3) * NN + n] = v;
                    }
                }
        }
    }
}

// ---------------------------------------------------------------------------
// Pass 2: one wave per node. R3: unconditional clamped gathers issued BEFORE
// softmax VALU work (mask folded into weight) -> 30-deep MLP per wave.
// ---------------------------------------------------------------------------
__global__ __launch_bounds__(256) void gat_pass2(
    const int* __restrict__ nidx, const float* __restrict__ edges,
    const float* __restrict__ zn_src, const float* __restrict__ s1,
    const float* __restrict__ c2, const float* __restrict__ bv,
    float* __restrict__ out)
{
    const int lane = threadIdx.x & 63;
    const int n    = (int)((blockIdx.x * blockDim.x + threadIdx.x) >> 6);
    if (n >= NN) return;

    int id[KK]; float ed[KK]; int sa[KK];
#pragma unroll
    for (int k = 0; k < KK; ++k) {
        id[k] = nidx[n * KK + k];
        ed[k] = edges[n * KK + k];
        sa[k] = max(id[k], 0);
    }

    float g[NH][KK];
#pragma unroll
    for (int k = 0; k < KK; ++k) {
        const float* rowp = zn_src + (size_t)sa[k] * OUTC + lane;
#pragma unroll
        for (int h = 0; h < NH; ++h) g[h][k] = rowp[h * FILT];
    }

    float npart = 0.f;
#pragma unroll
    for (int k = 0; k < KK; ++k) npart += (id[k] >= 0) ? 1.f : 0.f;
    const float rnorm = 1.f / fmaxf(npart, 1.f);

    float zacc[NH];
#pragma unroll
    for (int h = 0; h < NH; ++h) {
        const float c2v = c2[h * NN + n];
        float e[KK];
#pragma unroll
        for (int k = 0; k < KK; ++k) {
            float ev = (s1[h * NN + sa[k]] + c2v) * ed[k];
            e[k] = (id[k] >= 0) ? ev : 0.f;
        }
        float mx = e[0];
#pragma unroll
        for (int k = 1; k < KK; ++k) mx = fmaxf(mx, e[k]);
        float den = 0.f; float wk[KK];
#pragma unroll
        for (int k = 0; k < KK; ++k) { wk[k] = __expf(e[k] - mx); den += wk[k]; }
        const float scale = rnorm / den;
        float acc = 0.f;
#pragma unroll
        for (int k = 0; k < KK; ++k)
            acc = fmaf(g[h][k], (id[k] >= 0) ? wk[k] * scale : 0.f, acc);
        zacc[h] = acc;
    }

    float* orow = out + (size_t)n * OUTC;
#pragma unroll
    for (int h = 0; h < NH; ++h) {
        float res = orow[h * FILT + lane] + zacc[h] + bv[h * FILT + lane];
        orow[h * FILT + lane] = fmaxf(res, 0.f);
    }
}

// ---------------------------------------------------------------------------
extern "C" void kernel_launch(void* const* d_in, const int* in_sizes, int n_in,
                              void* d_out, int out_size, void* d_ws, size_t ws_size,
                              hipStream_t stream)
{
    const float* v_int  = (const float*)d_in[0];
    const float* v_nh   = (const float*)d_in[1];
    const int*   nh_idx = (const int*)d_in[2];
    const int*   in_idx = (const int*)d_in[3];
    const float* nh_e   = (const float*)d_in[4];
    const float* in_e   = (const float*)d_in[5];
    const int*   is_int = (const int*)d_in[6];
    const float* Wvc_i  = (const float*)d_in[7];
    const float* Wvc_n  = (const float*)d_in[8];
    const float* Wvn_i  = (const float*)d_in[9];
    const float* Wvn_n  = (const float*)d_in[10];
    const float* bv_i   = (const float*)d_in[11];
    const float* bv_n   = (const float*)d_in[12];
    const float* a_i    = (const float*)d_in[13];
    const float* a_n    = (const float*)d_in[14];

    float* out  = (float*)d_out;
    float* out2 = out + (size_t)NN * OUTC;

    // ws: zn_src (76.8MB) + s1 + c2 (2.4MB) + wt/wa ushort region (0.4MB)
    float* zn_src = (float*)d_ws;
    float* s1     = zn_src + (size_t)NN * OUTC;
    float* c2     = s1 + (size_t)NH * NN;
    u16*   wsu    = (u16*)(c2 + (size_t)NH * NN);

    dim3 b(256);

    gat_prep<<<400, b, 0, stream>>>(Wvc_i, Wvn_i, Wvc_n, Wvn_n, a_i, a_n, wsu);

    // int branch
    gat_pass1<<<NB, b, 0, stream>>>(v_int, is_int, 1,
                                    wsu, wsu + WA_OFF,
                                    out, zn_src, s1, c2);
    gat_pass2<<<(NN * 64) / 256, b, 0, stream>>>(in_idx, in_e, zn_src, s1, c2, bv_i, out);

    // nh branch
    gat_pass1<<<NB, b, 0, stream>>>(v_nh, is_int, 0,
                                    wsu + WT_BR_STRIDE, wsu + WA_OFF + WA_BR_STRIDE,
                                    out2, zn_src, s1, c2);
    gat_pass2<<<(NN * 64) / 256, b, 0, stream>>>(nh_idx, nh_e, zn_src, s1, c2, bv_n, out2);
}

// Round 6
// 581.881 us; speedup vs baseline: 18.6301x; 1.0037x over previous
//
#include <hip/hip_runtime.h>

// R4: pass2 restructured — wave-parallel softmax (lane=(h,k), 16-group shfl
//     reduces), float4 row-gathers via readlane SGPR base (10 loads/wave vs
//     30), wave-uniform skip of id<0 edges. R3 pass2 was VALU-issue-bound
//     (VALUBusy 72.6%, hbm 48%): ~250 instrs/wave -> ~120.
// R3: pass1 = split-bf16 MFMA, a-dots folded via prep (wa = W·a), W
//     pre-swizzled to frag layout (linear global_load_lds, rule #21).
// R2: unroll-2 fixed scratch spill (FETCH 6.87e6 -> 0.38e6 KB).

#define NN   100000
#define VFD  128
#define FILT 64
#define NH   3
#define KK   10
#define OUTC 192
#define NB   ((NN + 63) / 64)   // 1563

typedef __attribute__((ext_vector_type(8))) short  short8;
typedef __attribute__((ext_vector_type(4))) float  f32x4;
typedef __attribute__((ext_vector_type(8))) __bf16 bf16x8;
typedef unsigned int u32;
typedef unsigned short u16;

static __device__ __forceinline__ f32x4 mfma_bf16(short8 a, short8 b, f32x4 c) {
    return __builtin_amdgcn_mfma_f32_16x16x32_bf16(
        __builtin_bit_cast(bf16x8, a), __builtin_bit_cast(bf16x8, b), c, 0, 0, 0);
}

// x == hi + lo up to 2^-16 relative (truncation split; residual exact in fp32)
static __device__ __forceinline__ void split2(float x, u16 &hi, u16 &lo) {
    u32 b = __float_as_uint(x);
    hi = (u16)(b >> 16);
    float hf = __uint_as_float(((u32)hi) << 16);
    lo = (u16)(__float_as_uint(x - hf) >> 16);
}

static __device__ __forceinline__ void gload16(const u32* g, u32* l) {
    __builtin_amdgcn_global_load_lds(
        (const __attribute__((address_space(1))) u32*)g,
        (__attribute__((address_space(3))) u32*)l, 16, 0, 0);
}

// ---- ws ushort-region layout (after float region) ----
#define WT_CH_STRIDE   (2 * 8192)
#define WT_BR_STRIDE   (6 * WT_CH_STRIDE)
#define WA_OFF         (2 * WT_BR_STRIDE)
#define WA_BR_STRIDE   2048
#define PREP_WT_ELEMS  (2 * 6 * 8192)   // 98304
#define PREP_WA_ELEMS  (2 * 16 * VFD)   // 4096

__global__ void gat_prep(
    const float* __restrict__ Wvc_i, const float* __restrict__ Wvn_i,
    const float* __restrict__ Wvc_n, const float* __restrict__ Wvn_n,
    const float* __restrict__ a_i,  const float* __restrict__ a_n,
    u16* __restrict__ wsu)
{
    int t = blockIdx.x * blockDim.x + threadIdx.x;
    if (t < PREP_WT_ELEMS) {
        int b  = t / (6 * 8192);
        int r  = t % (6 * 8192);
        int ch = r / 8192;
        int e  = r % 8192;
        int f = e >> 6, col = e & 63;
        int m = ch / 3, h = ch % 3;
        const float* W = b ? (m ? Wvn_n : Wvc_n) : (m ? Wvn_i : Wvc_i);
        float val = W[h * (VFD * FILT) + f * FILT + col];
        u16 hi, lo; split2(val, hi, lo);
        int g    = f >> 3;
        int gran = g * 64 + (col ^ (g & 7));
        int idx  = gran * 8 + (f & 7);
        u16* dst = wsu + b * WT_BR_STRIDE + ch * WT_CH_STRIDE;
        dst[idx]        = hi;
        dst[8192 + idx] = lo;
    } else if (t < PREP_WT_ELEMS + PREP_WA_ELEMS) {
        int r = t - PREP_WT_ELEMS;
        int b = r / 2048, e = r % 2048;
        int col = e >> 7, f = e & 127;
        const float* a  = b ? a_n  : a_i;
        const float* Wc = b ? Wvc_n : Wvc_i;
        const float* Wn = b ? Wvn_n : Wvn_i;
        float val = 0.f;
        if (col < 3) {                       // c2 col: Wvc[h] row f · a2[h]
            const float* wr = Wc + col * (VFD * FILT) + f * FILT;
            const float* av = a  + col * (2 * FILT) + FILT;
            for (int o = 0; o < FILT; ++o) val += wr[o] * av[o];
        } else if (col < 6) {                // s1 col: Wvn[h] row f · a1[h]
            int h = col - 3;
            const float* wr = Wn + h * (VFD * FILT) + f * FILT;
            const float* av = a  + h * (2 * FILT);
            for (int o = 0; o < FILT; ++o) val += wr[o] * av[o];
        }
        int idx = ((f >> 3) * 16 + col) * 8 + (f & 7);
        wsu[WA_OFF + b * WA_BR_STRIDE + idx] = (u16)(__float_as_uint(val) >> 16);
    }
}

// ---------------------------------------------------------------------------
// Pass 1 (unchanged from R3): 64x64 tile, 4 waves 2x2, split-bf16 MFMA,
// fused wa GEMV epilogue -> c2/s1.
// ---------------------------------------------------------------------------
__global__ __launch_bounds__(256, 2) void gat_pass1(
    const float* __restrict__ vert, const int* __restrict__ is_int, int want,
    const u16* __restrict__ wt_ws, const u16* __restrict__ wa_ws,
    float* __restrict__ zc_out, float* __restrict__ zn_src,
    float* __restrict__ s1, float* __restrict__ c2)
{
    __shared__ __align__(16) u16 vt_hi[8192];
    __shared__ __align__(16) u16 vt_lo[8192];
    __shared__ __align__(16) u16 wt[2 * 8192];
    __shared__ __align__(16) u16 wa[2048];

    const int tid  = threadIdx.x;
    const int row0 = blockIdx.x * 64;
    const int w    = tid >> 6;
    const int lane = tid & 63;
    const int rw = w >> 1, cw = w & 1;
    const int l15 = lane & 15, l4 = lane >> 4;

#pragma unroll
    for (int i = 0; i < 8; ++i) {
        int idx4 = i * 256 + tid;
        int row = idx4 >> 5, f4 = idx4 & 31;
        int n = row0 + row;
        float4 val = make_float4(0.f, 0.f, 0.f, 0.f);
        if (n < NN && is_int[n] == want)
            val = *reinterpret_cast<const float4*>(vert + (size_t)n * VFD + f4 * 4);
        u16 h0,h1,h2,h3, q0,q1,q2,q3;
        split2(val.x, h0, q0); split2(val.y, h1, q1);
        split2(val.z, h2, q2); split2(val.w, h3, q3);
        int g    = f4 >> 1;
        int gran = g * 64 + (row ^ (g & 7));
        int uidx = gran * 8 + (f4 & 1) * 4;
        uint2 hv = make_uint2((u32)h0 | ((u32)h1 << 16), (u32)h2 | ((u32)h3 << 16));
        uint2 lv = make_uint2((u32)q0 | ((u32)q1 << 16), (u32)q2 | ((u32)q3 << 16));
        *reinterpret_cast<uint2*>(vt_hi + uidx) = hv;
        *reinterpret_cast<uint2*>(vt_lo + uidx) = lv;
    }
    gload16((const u32*)(wa_ws + tid * 8), (u32*)(wa + tid * 8));

    for (int ch = 0; ch < 6; ++ch) {
        __syncthreads();
        const u16* src = wt_ws + ch * WT_CH_STRIDE;
#pragma unroll
        for (int j = 0; j < 8; ++j) {
            int cblk = j * 256 + tid;
            gload16((const u32*)(src + cblk * 8), (u32*)(wt + cblk * 8));
        }
        __syncthreads();

        const int m = ch / 3, h = ch % 3;
        f32x4 zero = {0.f, 0.f, 0.f, 0.f};
        f32x4 acc[2][2] = {{zero, zero}, {zero, zero}};

#pragma unroll
        for (int ks = 0; ks < 4; ++ks) {
            const int g = ks * 4 + l4;
            short8 ahi[2], alo[2], bhi[2], blo[2];
#pragma unroll
            for (int ti = 0; ti < 2; ++ti) {
                int row  = (rw * 2 + ti) * 16 + l15;
                int gran = g * 64 + (row ^ (g & 7));
                ahi[ti] = *reinterpret_cast<const short8*>(vt_hi + gran * 8);
                alo[ti] = *reinterpret_cast<const short8*>(vt_lo + gran * 8);
            }
#pragma unroll
            for (int tj = 0; tj < 2; ++tj) {
                int col  = (cw * 2 + tj) * 16 + l15;
                int gran = g * 64 + (col ^ (g & 7));
                bhi[tj] = *reinterpret_cast<const short8*>(wt + gran * 8);
                blo[tj] = *reinterpret_cast<const short8*>(wt + 8192 + gran * 8);
            }
#pragma unroll
            for (int ti = 0; ti < 2; ++ti)
#pragma unroll
                for (int tj = 0; tj < 2; ++tj) {
                    acc[ti][tj] = mfma_bf16(ahi[ti], bhi[tj], acc[ti][tj]);
                    acc[ti][tj] = mfma_bf16(ahi[ti], blo[tj], acc[ti][tj]);
                    acc[ti][tj] = mfma_bf16(alo[ti], bhi[tj], acc[ti][tj]);
                }
        }

        float* target = (m == 0) ? zc_out : zn_src;
#pragma unroll
        for (int ti = 0; ti < 2; ++ti)
#pragma unroll
            for (int tj = 0; tj < 2; ++tj) {
                int col = (cw * 2 + tj) * 16 + l15;
#pragma unroll
                for (int j = 0; j < 4; ++j) {
                    int n = row0 + (rw * 2 + ti) * 16 + l4 * 4 + j;
                    if (n < NN) target[(size_t)n * OUTC + h * FILT + col] = acc[ti][tj][j];
                }
            }
    }

    {
        f32x4 zero = {0.f, 0.f, 0.f, 0.f};
        f32x4 accS[2] = {zero, zero};
#pragma unroll
        for (int ks = 0; ks < 4; ++ks) {
            const int g = ks * 4 + l4;
            short8 wf = *reinterpret_cast<const short8*>(wa + (g * 16 + l15) * 8);
#pragma unroll
            for (int ti = 0; ti < 2; ++ti) {
                int row  = (rw * 2 + ti) * 16 + l15;
                int gran = g * 64 + (row ^ (g & 7));
                short8 ahi = *reinterpret_cast<const short8*>(vt_hi + gran * 8);
                short8 alo = *reinterpret_cast<const short8*>(vt_lo + gran * 8);
                accS[ti] = mfma_bf16(ahi, wf, accS[ti]);
                accS[ti] = mfma_bf16(alo, wf, accS[ti]);
            }
        }
        if (cw == 0 && l15 < 6) {
#pragma unroll
            for (int ti = 0; ti < 2; ++ti)
#pragma unroll
                for (int j = 0; j < 4; ++j) {
                    int n = row0 + (rw * 2 + ti) * 16 + l4 * 4 + j;
                    if (n < NN) {
                        float v = accS[ti][j];
                        if (l15 < 3) c2[l15 * NN + n] = v;
                        else         s1[(l15 - 3) * NN + n] = v;
                    }
                }
        }
    }
}

// ---------------------------------------------------------------------------
// Pass 2 (R4): one wave per node.
//   lane l: (h,k) = (l>>4, l&15). Softmax wave-parallel: 16-group shfl_xor
//   reduces (max, den). Gathers: lanes 0..47 read float4 of row sa[k]
//   (SGPR base via readlane); id<0 edges skipped wave-uniformly (weight=0).
// ---------------------------------------------------------------------------
__global__ __launch_bounds__(256) void gat_pass2(
    const int* __restrict__ nidx, const float* __restrict__ edges,
    const float* __restrict__ zn_src, const float* __restrict__ s1,
    const float* __restrict__ c2, const float* __restrict__ bv,
    float* __restrict__ out)
{
    const int l = threadIdx.x & 63;
    const int n = (int)((blockIdx.x * blockDim.x + threadIdx.x) >> 6);
    if (n >= NN) return;

    const int k16 = l & 15;
    const int h   = l >> 4;                  // 0..3 (group 3 idle for compute)
    const int hc  = (h < 3) ? h : 2;

    // lanes 0..9 load this node's idx/edge
    int   idv = -1;
    float edv = 0.f;
    if (l < KK) {
        idv = nidx[n * KK + l];
        edv = edges[n * KK + l];
    }
    const unsigned long long vm = __ballot(l < KK && idv >= 0);
    const float rnorm = 1.f / fmaxf((float)__popcll(vm), 1.f);

    // score e[h][k] on lane (h,k)
    const int   idb = __shfl(idv, k16);
    const float edb = __shfl(edv, k16);
    const int   sab = max(idb, 0);
    const bool  kvalid = (k16 < KK);
    const bool  evalid = kvalid && (idb >= 0);
    const float c2v = c2[hc * NN + n];
    const float s1v = s1[hc * NN + sab];     // 4B scattered, 1.2MB L2-hot
    const float e   = evalid ? (s1v + c2v) * edb : 0.f;

    // 16-group reductions (xor masks 1,2,4,8 stay within the group)
    float er = kvalid ? e : -3.4e38f;
#pragma unroll
    for (int m = 1; m < 16; m <<= 1) er = fmaxf(er, __shfl_xor(er, m));
    const float wk = kvalid ? __expf(e - er) : 0.f;   // e=0 rows participate, as in ref
    float dn = wk;
#pragma unroll
    for (int m = 1; m < 16; m <<= 1) dn += __shfl_xor(dn, m);
    const float wfin = evalid ? wk * (rnorm / dn) : 0.f;

    // gather + FMA: lanes 0..47 own float4 (h = l*4/64, f = (l*4)%64 ..+3)
    const bool act = (l < 48);
    float4 acc = make_float4(0.f, 0.f, 0.f, 0.f);
#pragma unroll
    for (int k = 0; k < KK; ++k) {
        const int idk = __builtin_amdgcn_readlane(idv, k);   // SGPR
        if (idk >= 0) {                                       // wave-uniform skip
            const float wb = __shfl(wfin, k, 16);             // per-16-group bcast
            if (act) {
                const float4 g = *reinterpret_cast<const float4*>(
                    zn_src + (size_t)idk * OUTC + l * 4);
                acc.x = fmaf(g.x, wb, acc.x);
                acc.y = fmaf(g.y, wb, acc.y);
                acc.z = fmaf(g.z, wb, acc.z);
                acc.w = fmaf(g.w, wb, acc.w);
            }
        }
    }

    if (act) {
        float* op = out + (size_t)n * OUTC + l * 4;
        const float4 zc = *reinterpret_cast<const float4*>(op);
        const float4 bq = *reinterpret_cast<const float4*>(bv + l * 4);
        float4 r;
        r.x = fmaxf(zc.x + acc.x + bq.x, 0.f);
        r.y = fmaxf(zc.y + acc.y + bq.y, 0.f);
        r.z = fmaxf(zc.z + acc.z + bq.z, 0.f);
        r.w = fmaxf(zc.w + acc.w + bq.w, 0.f);
        *reinterpret_cast<float4*>(op) = r;
    }
}

// ---------------------------------------------------------------------------
extern "C" void kernel_launch(void* const* d_in, const int* in_sizes, int n_in,
                              void* d_out, int out_size, void* d_ws, size_t ws_size,
                              hipStream_t stream)
{
    const float* v_int  = (const float*)d_in[0];
    const float* v_nh   = (const float*)d_in[1];
    const int*   nh_idx = (const int*)d_in[2];
    const int*   in_idx = (const int*)d_in[3];
    const float* nh_e   = (const float*)d_in[4];
    const float* in_e   = (const float*)d_in[5];
    const int*   is_int = (const int*)d_in[6];
    const float* Wvc_i  = (const float*)d_in[7];
    const float* Wvc_n  = (const float*)d_in[8];
    const float* Wvn_i  = (const float*)d_in[9];
    const float* Wvn_n  = (const float*)d_in[10];
    const float* bv_i   = (const float*)d_in[11];
    const float* bv_n   = (const float*)d_in[12];
    const float* a_i    = (const float*)d_in[13];
    const float* a_n    = (const float*)d_in[14];

    float* out  = (float*)d_out;
    float* out2 = out + (size_t)NN * OUTC;

    float* zn_src = (float*)d_ws;
    float* s1     = zn_src + (size_t)NN * OUTC;
    float* c2     = s1 + (size_t)NH * NN;
    u16*   wsu    = (u16*)(c2 + (size_t)NH * NN);

    dim3 b(256);

    gat_prep<<<400, b, 0, stream>>>(Wvc_i, Wvn_i, Wvc_n, Wvn_n, a_i, a_n, wsu);

    // int branch
    gat_pass1<<<NB, b, 0, stream>>>(v_int, is_int, 1,
                                    wsu, wsu + WA_OFF,
                                    out, zn_src, s1, c2);
    gat_pass2<<<(NN * 64) / 256, b, 0, stream>>>(in_idx, in_e, zn_src, s1, c2, bv_i, out);

    // nh branch
    gat_pass1<<<NB, b, 0, stream>>>(v_nh, is_int, 0,
                                    wsu + WT_BR_STRIDE, wsu + WA_OFF + WA_BR_STRIDE,
                                    out2, zn_src, s1, c2);
    gat_pass2<<<(NN * 64) / 256, b, 0, stream>>>(nh_idx, nh_e, zn_src, s1, c2, bv_n, out2);
}